// Round 5
// baseline (3329.958 us; speedup 1.0000x reference)
//
#include <hip/hip_runtime.h>
#include <stdint.h>

typedef _Float16 f16;
typedef f16 f16x8 __attribute__((ext_vector_type(8)));
typedef f16 f16x4 __attribute__((ext_vector_type(4)));
typedef float f32x4 __attribute__((ext_vector_type(4)));
typedef int i32x4 __attribute__((ext_vector_type(4)));

#define DEV __device__ __forceinline__

// ---------------- workspace layout (bytes) ----------------
// W blobs: per design, fragment blobs of 1KB, order [wave][nt][kt], within blob lane*16B.
static const size_t OFF_W1 = 0;                                  // 640 blobs * 1024
static const size_t OFF_W2 = OFF_W1 + (size_t)640 * 1024;        // 640 blobs
static const size_t OFF_W3 = OFF_W2 + (size_t)640 * 1024;        // 160 blobs
static const size_t OFF_B1 = OFF_W3 + (size_t)160 * 1024;        // 1024 f32 (orig order)
static const size_t OFF_B2 = OFF_B1 + 4096;
static const size_t OFF_B3 = OFF_B2 + 4096;                      // 512 f32
static const size_t OFF_FEAT = OFF_B3 + 2048;                    // 512*3840 f32
static const size_t WS_NEEDED = OFF_FEAT + (size_t)512 * 3840 * 4;

DEV float sigm(float x) { return 1.f / (1.f + __expf(-x)); }
DEV float tanh_(float x) { return 1.f - 2.f / (__expf(2.f * x) + 1.f); }

// MFMA via inline asm: acc pinned to AGPR ("+a"); weight operand from VGPR ("v")
// or AGPR ("a") so W can live in the otherwise-idle AGPR half of the unified file.
DEV void mfma_bv(f32x4& acc, i32x4 a, i32x4 b) {
  asm("v_mfma_f32_16x16x32_f16 %0, %1, %2, %0" : "+a"(acc) : "v"(a), "v"(b));
}
DEV void mfma_ba(f32x4& acc, i32x4 a, i32x4 b) {
  asm("v_mfma_f32_16x16x32_f16 %0, %1, %2, %0" : "+a"(acc) : "v"(a), "a"(b));
}

// ---------------- prep: pack weights into fragment blobs (fp16) ----------------
template <int H, int IN, int NT, int NKT>
DEV void packW(const float* __restrict__ Wih, const float* __restrict__ Whh,
               f16* __restrict__ dst, int i) {
  int e = i & 7, lane = (i >> 3) & 63;
  int rest = i >> 9;
  int kt = rest % NKT; rest /= NKT;
  int nt = rest % NT;  int w = rest / NT;
  int quad = lane >> 4, l16 = lane & 15;
  constexpr int NTG = NT / 4, UW = NT * 4;
  int unit = w * UW + (nt % NTG) * 16 + l16;
  int g = nt / NTG;
  int r = g * H + unit;
  int k = kt * 32 + quad * 8 + e;
  float v = (k < IN) ? Wih[r * IN + k] : Whh[r * H + (k - IN)];
  dst[i] = (f16)v;
}

__global__ void prep_kernel(const float* __restrict__ Wih1, const float* __restrict__ Whh1,
                            const float* __restrict__ bih1, const float* __restrict__ bhh1,
                            const float* __restrict__ Wih2, const float* __restrict__ Whh2,
                            const float* __restrict__ bih2, const float* __restrict__ bhh2,
                            const float* __restrict__ Wih3, const float* __restrict__ Whh3,
                            const float* __restrict__ bih3, const float* __restrict__ bhh3,
                            uint8_t* __restrict__ ws) {
  const int gt = blockIdx.x * blockDim.x + threadIdx.x;
  const int gs = gridDim.x * blockDim.x;
  f16* W1 = (f16*)(ws + OFF_W1);
  f16* W2 = (f16*)(ws + OFF_W2);
  f16* W3 = (f16*)(ws + OFF_W3);
  float* B1 = (float*)(ws + OFF_B1);
  float* B2 = (float*)(ws + OFF_B2);
  float* B3 = (float*)(ws + OFF_B3);
  for (int i = gt; i < 640 * 512; i += gs) {
    packW<256, 64, 16, 10>(Wih1, Whh1, W1, i);
    packW<256, 64, 16, 10>(Wih2, Whh2, W2, i);
  }
  for (int i = gt; i < 160 * 512; i += gs) packW<128, 32, 8, 5>(Wih3, Whh3, W3, i);
  for (int i = gt; i < 1024; i += gs) { B1[i] = bih1[i] + bhh1[i]; B2[i] = bih2[i] + bhh2[i]; }
  for (int i = gt; i < 512; i += gs) B3[i] = bih3[i] + bhh3[i];
}

// ---------------- persistent LSTM tile, zero inter-block comm ----------------
// Block = 256 thr = 4 waves, 1 block/CU. Block owns BM rows x ALL 4H gate cols; wave w
// owns units [w*UW,(w+1)*UW). h lives in LDS A=[x_t|h]. W classes by nt position:
// [0,NVV) VGPR, [NVV,NVV+NVA) AGPR, next NL LDS-resident, last NS streamed from L2,
// opposite-slot depth-1 double buffer (round-3-proven discipline: prime slot 0, load
// slot pn<-slice kt+1 during kt, use slot pc=kt&1). __syncthreads barriers (full
// vmcnt drain accepted -- correctness-proven; the drain stall is ~150 cyc/step).
template <int BM, int IN, int H, int T, int NT, int NKT, int NVV, int NVA, int NL, int NS,
          int DOM>
DEV void lstm_tile5(const float* __restrict__ x0, const float* __restrict__ x1, int halfM,
                    const f16* __restrict__ Wd, const float* __restrict__ bsum,
                    float* __restrict__ feat, int mg, uint8_t* smem) {
  static_assert(NVV + NVA + NL + NS == NT, "split");
  static_assert((NL == 0 && NS == 0) || (NKT % 2 == 0), "wrap parity");
  constexpr int MT = BM / 16;
  constexpr int NTG = NT / 4;
  constexpr int UW = NT * 4;
  constexpr int KCH = (IN + H) / 8;
  constexpr int SROW = KCH + 1;      // +1 chunk pad -> bank rotate per row
  constexpr int AROWE = SROW * 8;
  constexpr int XPT = BM * IN / 4 / 256;

  const int tid = threadIdx.x;
  const int lane = tid & 63;
  const int w = tid >> 6;
  const int quad = lane >> 4;
  const int l16 = lane & 15;
  const int rowbase = mg * BM;

  f16* A = (f16*)smem;
  f16* Wshm = (f16*)(smem + (size_t)BM * AROWE * 2);

  const float* xb = (rowbase < halfM) ? x0 : x1;
  const int rowoff = rowbase - ((rowbase < halfM) ? 0 : halfM);

  // zero h-region of A
  {
    constexpr int HCH = KCH - IN / 8;
    for (int i = tid; i < BM * HCH * 4; i += 256) {
      int row = i / (HCH * 4), rem = i % (HCH * 4);
      int chunk = IN / 8 + rem / 4, d = rem % 4;
      ((uint32_t*)A)[row * SROW * 4 + chunk * 4 + d] = 0;
    }
  }
  // stage LDS-resident W frags
  if constexpr (NL > 0) {
    for (int idx = tid; idx < 4 * NL * NKT * 64; idx += 256) {
      int ln = idx & 63;
      int kt = (idx >> 6) % NKT;
      int rest = (idx >> 6) / NKT;
      int nl = rest % NL, w2 = rest / NL;
      int blob = (w2 * NT + NVV + NVA + nl) * NKT + kt;
      *(i32x4*)(Wshm + (size_t)((w2 * NL + nl) * NKT + kt) * 512 + ln * 8) =
          *(const i32x4*)(Wd + (size_t)blob * 512 + ln * 8);
    }
  }
  // VGPR-resident W
  i32x4 wregv[NVV > 0 ? NVV : 1][NKT];
  {
    const f16* Wv = Wd + (size_t)(w * NT) * NKT * 512 + lane * 8;
#pragma unroll
    for (int nt = 0; nt < NVV; ++nt)
#pragma unroll
      for (int kt = 0; kt < NKT; ++kt)
        wregv[nt][kt] = *(const i32x4*)(Wv + (size_t)(nt * NKT + kt) * 512);
  }
  // AGPR-resident W (all uses via "a" asm constraint -> allocator places in AGPRs)
  i32x4 wrega[NVA > 0 ? NVA : 1][NKT];
  {
    const f16* Wa = Wd + (size_t)(w * NT + NVV) * NKT * 512 + lane * 8;
#pragma unroll
    for (int nt = 0; nt < NVA; ++nt)
#pragma unroll
      for (int kt = 0; kt < NKT; ++kt)
        wrega[nt][kt] = *(const i32x4*)(Wa + (size_t)(nt * NKT + kt) * 512);
  }
  const f16* Wstream = Wd + (size_t)(w * NT + NVV + NVA + NL) * NKT * 512 + lane * 8;

  // biases (per lane: its unit, per nt slot); pre-added via acc init
  float bias[NT];
#pragma unroll
  for (int nt = 0; nt < NT; ++nt)
    bias[nt] = bsum[(nt / NTG) * H + w * UW + (nt % NTG) * 16 + l16];

  i32x4 sbuf[2][NS > 0 ? NS : 1];
  i32x4 wlds[2][NL > 0 ? NL : 1];

  // stage x(0)
  float4 xr[XPT];
#pragma unroll
  for (int i = 0; i < XPT; ++i) {
    int idx = i * 256 + tid;
    int row = idx / (IN / 4), c4 = idx % (IN / 4);
    xr[i] = *(const float4*)(xb + (size_t)(rowoff + row) * T * IN + c4 * 4);
  }
#pragma unroll
  for (int i = 0; i < XPT; ++i) {
    int idx = i * 256 + tid;
    int row = idx / (IN / 4), c4 = idx % (IN / 4);
    int k = c4 * 4;
    f16x4 p;
    p[0] = (f16)xr[i].x; p[1] = (f16)xr[i].y; p[2] = (f16)xr[i].z; p[3] = (f16)xr[i].w;
    *(f16x4*)(A + row * AROWE + (k >> 3) * 8 + (k & 7)) = p;
  }
  __syncthreads();
  // prime slot 0 (slice 0)
  if constexpr (NS > 0) {
#pragma unroll
    for (int ns = 0; ns < NS; ++ns)
      sbuf[0][ns] = *(const i32x4*)(Wstream + (size_t)(ns * NKT) * 512);
  }
  if constexpr (NL > 0) {
#pragma unroll
    for (int nl = 0; nl < NL; ++nl)
      wlds[0][nl] = *(const i32x4*)(Wshm + (size_t)((w * NL + nl) * NKT) * 512 + lane * 8);
  }

  float c[MT * NTG * 4];
#pragma unroll
  for (int i = 0; i < MT * NTG * 4; ++i) c[i] = 0.f;

  f32x4 acc[NT][MT];
#pragma unroll
  for (int nt = 0; nt < NT; ++nt)
#pragma unroll
    for (int mt = 0; mt < MT; ++mt)
      acc[nt][mt] = f32x4{bias[nt], bias[nt], bias[nt], bias[nt]};

  i32x4 afbuf[2][MT];

#pragma unroll 1
  for (int t = 0; t < T; ++t) {
    // A-fragments for kt=0
#pragma unroll
    for (int mt = 0; mt < MT; ++mt)
      afbuf[0][mt] = *(const i32x4*)(A + (mt * 16 + l16) * AROWE + quad * 8);
    // prefetch x(t+1) (long-latency, overlaps whole K loop)
    if (t < T - 1) {
#pragma unroll
      for (int i = 0; i < XPT; ++i) {
        int idx = i * 256 + tid;
        int row = idx / (IN / 4), c4 = idx % (IN / 4);
        xr[i] =
            *(const float4*)(xb + (size_t)(rowoff + row) * T * IN + (size_t)(t + 1) * IN + c4 * 4);
      }
    }
    // K loop: opposite-slot depth-1 prefetch (round-3-proven)
#pragma unroll
    for (int kt = 0; kt < NKT; ++kt) {
      const int pc = kt & 1, pn = (kt + 1) & 1;
      const int ktn = (kt + 1) % NKT;
      if (kt + 1 < NKT) {
#pragma unroll
        for (int mt = 0; mt < MT; ++mt)
          afbuf[pn][mt] = *(const i32x4*)(A + (mt * 16 + l16) * AROWE + ((kt + 1) * 4 + quad) * 8);
      }
      if constexpr (NS > 0) {
#pragma unroll
        for (int ns = 0; ns < NS; ++ns)
          sbuf[pn][ns] = *(const i32x4*)(Wstream + (size_t)(ns * NKT + ktn) * 512);
      }
      if constexpr (NL > 0) {
#pragma unroll
        for (int nl = 0; nl < NL; ++nl)
          wlds[pn][nl] = *(const i32x4*)(Wshm + (size_t)((w * NL + nl) * NKT + ktn) * 512 + lane * 8);
      }
      // resident classes first; streamed last (max slack for in-flight loads)
#pragma unroll
      for (int nt = 0; nt < NVV; ++nt)
#pragma unroll
        for (int mt = 0; mt < MT; ++mt) mfma_bv(acc[nt][mt], afbuf[pc][mt], wregv[nt][kt]);
#pragma unroll
      for (int nt = 0; nt < NVA; ++nt)
#pragma unroll
        for (int mt = 0; mt < MT; ++mt) mfma_ba(acc[NVV + nt][mt], afbuf[pc][mt], wrega[nt][kt]);
      if constexpr (NL > 0) {
#pragma unroll
        for (int nl = 0; nl < NL; ++nl)
#pragma unroll
          for (int mt = 0; mt < MT; ++mt)
            mfma_bv(acc[NVV + NVA + nl][mt], afbuf[pc][mt], wlds[pc][nl]);
      }
      if constexpr (NS > 0) {
#pragma unroll
        for (int ns = 0; ns < NS; ++ns)
#pragma unroll
          for (int mt = 0; mt < MT; ++mt)
            mfma_bv(acc[NVV + NVA + NL + ns][mt], afbuf[pc][mt], sbuf[pc][ns]);
      }
    }
    __syncthreads();  // all A(t) reads done before h(t)/x(t+1) writes
    asm volatile("s_nop 7\n\ts_nop 7\n\ts_nop 7" ::);  // MFMA->v_accvgpr_read hazard pad

    // in-register activation: lane holds i,f,g,o of cell (row=mt*16+quad*4+j,
    // unit=w*UW+ut*16+l16) at acc[g*NTG+ut][mt][j]; bias already in acc
#pragma unroll
    for (int mt = 0; mt < MT; ++mt)
#pragma unroll
      for (int ut = 0; ut < NTG; ++ut)
#pragma unroll
        for (int j = 0; j < 4; ++j) {
          float gi = acc[0 * NTG + ut][mt][j];
          float gf = acc[1 * NTG + ut][mt][j];
          float gg = acc[2 * NTG + ut][mt][j];
          float go = acc[3 * NTG + ut][mt][j];
          int ci = (mt * NTG + ut) * 4 + j;
          float cc = sigm(gf) * c[ci] + sigm(gi) * tanh_(gg);
          c[ci] = cc;
          float hv = sigm(go) * tanh_(cc);
          int row = mt * 16 + quad * 4 + j;
          if (t < T - 1) {
            int k = IN + w * UW + ut * 16 + l16;
            A[row * AROWE + (k >> 3) * 8 + (k & 7)] = (f16)hv;
          } else {
            int R = rowbase + row;
            int unit = w * UW + ut * 16 + l16;
            int b, col;
            if (DOM == 0) {
              if (R < 512) { b = R; col = unit; }
              else         { b = R - 512; col = 256 + unit; }
            } else if (DOM == 1) {
              b = R; col = 512 + unit;
            } else {
              int rr = R; int base = 768;
              if (rr >= 6144) { rr -= 6144; base = 2304; }
              b = rr / 12; int p = rr - b * 12;
              col = base + p * 128 + unit;
            }
            feat[(size_t)b * 3840 + col] = hv;
          }
        }
    // re-init acc to bias for next step (VALU writes safely before the barrier)
#pragma unroll
    for (int nt = 0; nt < NT; ++nt)
#pragma unroll
      for (int mt = 0; mt < MT; ++mt)
        acc[nt][mt] = f32x4{bias[nt], bias[nt], bias[nt], bias[nt]};
    // write x(t+1)
    if (t < T - 1) {
#pragma unroll
      for (int i = 0; i < XPT; ++i) {
        int idx = i * 256 + tid;
        int row = idx / (IN / 4), c4 = idx % (IN / 4);
        int k = c4 * 4;
        f16x4 p;
        p[0] = (f16)xr[i].x; p[1] = (f16)xr[i].y; p[2] = (f16)xr[i].z; p[3] = (f16)xr[i].w;
        *(f16x4*)(A + row * AROWE + (k >> 3) * 8 + (k & 7)) = p;
      }
    }
    __syncthreads();
  }
}

// Grid = 240 blocks (32 D1 + 16 D2 + 192 D3) -- all co-resident on 256 CUs, no tail.
template <int NL1, int NS1>
DEV void lstm_body(const float* gh, const float* ga, const float* gv, const float* ph,
                   const float* pa, uint8_t* ws, uint8_t* smem) {
  float* feat = (float*)(ws + OFF_FEAT);
  int bid = blockIdx.x;
  if (bid < 32) {
    lstm_tile5<32, 64, 256, 128, 16, 10, 1, 3, NL1, NS1, 0>(
        gh, ga, 512, (const f16*)(ws + OFF_W1), (const float*)(ws + OFF_B1), feat, bid, smem);
  } else if (bid < 48) {
    lstm_tile5<32, 64, 256, 128, 16, 10, 1, 3, NL1, NS1, 1>(
        gv, gv, 512, (const f16*)(ws + OFF_W2), (const float*)(ws + OFF_B2), feat, bid - 32, smem);
  } else {
    lstm_tile5<64, 32, 128, 64, 8, 5, 3, 5, 0, 0, 2>(
        ph, pa, 6144, (const f16*)(ws + OFF_W3), (const float*)(ws + OFF_B3), feat, bid - 48, smem);
  }
}

__global__ __launch_bounds__(256, 1) void lstm_main_big(const float* __restrict__ gh,
                                                        const float* __restrict__ ga,
                                                        const float* __restrict__ gv,
                                                        const float* __restrict__ ph,
                                                        const float* __restrict__ pa,
                                                        uint8_t* __restrict__ ws) {
  extern __shared__ uint8_t smem[];
  lstm_body<3, 9>(gh, ga, gv, ph, pa, ws, smem);  // LDS: 20992 + 3*40960 = 143872
}

__global__ __launch_bounds__(256, 1) void lstm_main_small(const float* __restrict__ gh,
                                                          const float* __restrict__ ga,
                                                          const float* __restrict__ gv,
                                                          const float* __restrict__ ph,
                                                          const float* __restrict__ pa,
                                                          uint8_t* __restrict__ ws) {
  extern __shared__ uint8_t smem[];
  lstm_body<1, 11>(gh, ga, gv, ph, pa, ws, smem);  // LDS: 20992 + 40960 = 61952
}

// ---------------- final FC ----------------
__global__ void fc_kernel(const float* __restrict__ feat, const float* __restrict__ cg,
                          const float* __restrict__ Wfc, const float* __restrict__ bfc,
                          float* __restrict__ out) {
  int b = blockIdx.x, tid = threadIdx.x;
  float a0 = 0.f, a1 = 0.f;
  for (int c = tid; c < 3840; c += 256) {
    float f = feat[(size_t)b * 3840 + c];
    a0 += f * Wfc[c];
    a1 += f * Wfc[3872 + c];
  }
  if (tid < 32) {
    float f = cg[b * 32 + tid];
    a0 += f * Wfc[3840 + tid];
    a1 += f * Wfc[3872 + 3840 + tid];
  }
#pragma unroll
  for (int o = 32; o > 0; o >>= 1) {
    a0 += __shfl_down(a0, o);
    a1 += __shfl_down(a1, o);
  }
  __shared__ float red[8];
  int wv = tid >> 6;
  if ((tid & 63) == 0) { red[wv * 2] = a0; red[wv * 2 + 1] = a1; }
  __syncthreads();
  if (tid == 0) {
    out[b * 2 + 0] = red[0] + red[2] + red[4] + red[6] + bfc[0];
    out[b * 2 + 1] = red[1] + red[3] + red[5] + red[7] + bfc[1];
  }
}

extern "C" void kernel_launch(void* const* d_in, const int* in_sizes, int n_in, void* d_out,
                              int out_size, void* d_ws, size_t ws_size, hipStream_t stream) {
  const float* cg = (const float*)d_in[0];
  const float* gh = (const float*)d_in[1];
  const float* ga = (const float*)d_in[2];
  const float* gv = (const float*)d_in[3];
  const float* ph = (const float*)d_in[4];
  const float* pa = (const float*)d_in[5];
  const float* Wih1 = (const float*)d_in[6];
  const float* Whh1 = (const float*)d_in[7];
  const float* bih1 = (const float*)d_in[8];
  const float* bhh1 = (const float*)d_in[9];
  const float* Wih2 = (const float*)d_in[10];
  const float* Whh2 = (const float*)d_in[11];
  const float* bih2 = (const float*)d_in[12];
  const float* bhh2 = (const float*)d_in[13];
  const float* Wih3 = (const float*)d_in[14];
  const float* Whh3 = (const float*)d_in[15];
  const float* bih3 = (const float*)d_in[16];
  const float* bhh3 = (const float*)d_in[17];
  const float* Wfc = (const float*)d_in[18];
  const float* bfc = (const float*)d_in[19];
  uint8_t* ws = (uint8_t*)d_ws;
  if (ws_size < WS_NEEDED) return;

  hipLaunchKernelGGL(prep_kernel, dim3(512), dim3(256), 0, stream, Wih1, Whh1, bih1, bhh1,
                     Wih2, Whh2, bih2, bhh2, Wih3, Whh3, bih3, bhh3, ws);

  int dev = 0, maxShm = 0;
  (void)hipGetDevice(&dev);
  (void)hipDeviceGetAttribute(&maxShm, hipDeviceAttributeMaxSharedMemoryPerBlock, dev);
  hipError_t ae = hipFuncSetAttribute((const void*)lstm_main_big,
                                      hipFuncAttributeMaxDynamicSharedMemorySize, 143872);
  if (ae == hipSuccess && maxShm >= 143872) {
    hipLaunchKernelGGL(lstm_main_big, dim3(240), dim3(256), 143872, stream, gh, ga, gv, ph, pa, ws);
  } else {
    hipLaunchKernelGGL(lstm_main_small, dim3(240), dim3(256), 61952, stream, gh, ga, gv, ph, pa,
                       ws);
  }
  hipLaunchKernelGGL(fc_kernel, dim3(512), dim3(256), 0, stream,
                     (const float*)(ws + OFF_FEAT), cg, Wfc, bfc, (float*)d_out);
}